// Round 2
// baseline (2004.629 us; speedup 1.0000x reference)
//
#include <hip/hip_runtime.h>
#include <cstdint>

#define NNODES 100000
#define NEDGES 3200000
#define FEAT   256
#define EPS_BN 1e-5f

// ============================ CSR build ============================

__global__ void count_kernel(const int* __restrict__ rows, int* __restrict__ counts) {
  int stride = gridDim.x * blockDim.x;
  for (int e = blockIdx.x * blockDim.x + threadIdx.x; e < NEDGES; e += stride)
    atomicAdd(&counts[rows[e]], 1);
}

// single-block exclusive scan over counts[0..NNODES), writes offsets[0..NNODES] and cursor copy
__global__ __launch_bounds__(1024) void scan_kernel(const int* __restrict__ counts,
                                                    int* __restrict__ offsets,
                                                    int* __restrict__ cursor) {
  __shared__ int wsum[16];
  __shared__ int sbase;
  const int tid = threadIdx.x, lane = tid & 63, wid = tid >> 6;
  if (tid == 0) sbase = 0;
  __syncthreads();
  for (int start = 0; start < NNODES; start += 1024) {
    int i = start + tid;
    int x = (i < NNODES) ? counts[i] : 0;
    int v = x;
#pragma unroll
    for (int off = 1; off < 64; off <<= 1) {
      int u = __shfl_up(v, off);
      if (lane >= off) v += u;
    }
    if (lane == 63) wsum[wid] = v;
    __syncthreads();
    if (wid == 0 && lane < 16) {
      int wv = wsum[lane];
#pragma unroll
      for (int off = 1; off < 16; off <<= 1) {
        int u = __shfl_up(wv, off);
        if (lane >= off) wv += u;
      }
      wsum[lane] = wv;
    }
    __syncthreads();
    int base = sbase + ((wid > 0) ? wsum[wid - 1] : 0);
    int excl = base + v - x;
    if (i < NNODES) { offsets[i] = excl; cursor[i] = excl; }
    __syncthreads();
    if (tid == 0) sbase += wsum[15];
    __syncthreads();
  }
  if (tid == 0) offsets[NNODES] = sbase;
}

__global__ void scatter_kernel(const int* __restrict__ rows, const int* __restrict__ cols,
                               const float* __restrict__ vals, int* __restrict__ cursor,
                               int2* __restrict__ edges) {
  int stride = gridDim.x * blockDim.x;
  for (int e = blockIdx.x * blockDim.x + threadIdx.x; e < NEDGES; e += stride) {
    int r = rows[e];
    int pos = atomicAdd(&cursor[r], 1);
    edges[pos] = make_int2(cols[e], __float_as_int(vals[e]));
  }
}

// ============================ GEMM (fp32 vector) ============================
// C[M,256] = act(A)[M,256] @ B[256,256].  BM=BN=64, BK=32, 256 thr, 4x4/thread.
// BN=true: A element at K-column k is transformed relu(a*scale[k]+shift[k]) while staging.

template <bool BN>
__global__ __launch_bounds__(256) void gemm_kernel(const float* __restrict__ A,
                                                   const float* __restrict__ B,
                                                   float* __restrict__ C,
                                                   const float* __restrict__ scale,
                                                   const float* __restrict__ shift) {
  __shared__ float As[32][68];  // [k][m], padded for bank spread + 16B align
  __shared__ float Bs[32][68];  // [k][n]
  const int tid = threadIdx.x;
  const int row0 = blockIdx.x * 64;
  const int col0 = blockIdx.y * 64;
  const int rg = tid >> 4, cg = tid & 15;
  float acc[4][4] = {};

  for (int kt = 0; kt < 8; ++kt) {
    __syncthreads();
#pragma unroll
    for (int i = 0; i < 2; ++i) {
      int idx = tid + 256 * i;
      // A: 64 rows x 32 k = 512 float4 ; transpose into As[k][m]
      int ar = idx >> 3, akq = idx & 7;
      int grow = row0 + ar;
      float4 av = make_float4(0.f, 0.f, 0.f, 0.f);
      if (grow < NNODES)
        av = *(const float4*)&A[grow * FEAT + kt * 32 + akq * 4];
      if (BN) {
        int kb = kt * 32 + akq * 4;
        float4 sc = *(const float4*)&scale[kb];
        float4 sh = *(const float4*)&shift[kb];
        av.x = fmaxf(0.f, fmaf(av.x, sc.x, sh.x));
        av.y = fmaxf(0.f, fmaf(av.y, sc.y, sh.y));
        av.z = fmaxf(0.f, fmaf(av.z, sc.z, sh.z));
        av.w = fmaxf(0.f, fmaf(av.w, sc.w, sh.w));
      }
      As[akq * 4 + 0][ar] = av.x;
      As[akq * 4 + 1][ar] = av.y;
      As[akq * 4 + 2][ar] = av.z;
      As[akq * 4 + 3][ar] = av.w;
      // B: 32 k x 64 n = 512 float4 ; natural layout
      int bk = idx >> 4, bq = idx & 15;
      float4 bv = *(const float4*)&B[(kt * 32 + bk) * FEAT + col0 + bq * 4];
      *(float4*)&Bs[bk][bq * 4] = bv;
    }
    __syncthreads();
#pragma unroll
    for (int k = 0; k < 32; ++k) {
      float4 a4 = *(const float4*)&As[k][rg * 4];
      float4 b4 = *(const float4*)&Bs[k][cg * 4];
      float av_[4] = {a4.x, a4.y, a4.z, a4.w};
      float bv_[4] = {b4.x, b4.y, b4.z, b4.w};
#pragma unroll
      for (int ii = 0; ii < 4; ++ii)
#pragma unroll
        for (int jj = 0; jj < 4; ++jj)
          acc[ii][jj] = fmaf(av_[ii], bv_[jj], acc[ii][jj]);
    }
  }
#pragma unroll
  for (int i = 0; i < 4; ++i) {
    int r = row0 + rg * 4 + i;
    if (r < NNODES)
      *(float4*)&C[r * FEAT + col0 + cg * 4] =
          make_float4(acc[i][0], acc[i][1], acc[i][2], acc[i][3]);
  }
}

// ============================ SpMM: Y = (A+I) @ X ============================
// One wave per destination row; lane holds float4 (256 feats / 64 lanes).

__global__ __launch_bounds__(256) void spmm_kernel(const float* __restrict__ X,
                                                   const int* __restrict__ offsets,
                                                   const int2* __restrict__ edges,
                                                   float* __restrict__ Y) {
  const int lane = threadIdx.x & 63;
  const int row = blockIdx.x * 4 + (threadIdx.x >> 6);
  if (row >= NNODES) return;
  const int s = offsets[row], e = offsets[row + 1];
  const float4* __restrict__ X4 = (const float4*)X;
  float4 acc = make_float4(0.f, 0.f, 0.f, 0.f);
  int j = s;
  for (; j + 4 <= e; j += 4) {
    int2 p0 = edges[j], p1 = edges[j + 1], p2 = edges[j + 2], p3 = edges[j + 3];
    float4 x0 = X4[p0.x * 64 + lane];
    float4 x1 = X4[p1.x * 64 + lane];
    float4 x2 = X4[p2.x * 64 + lane];
    float4 x3 = X4[p3.x * 64 + lane];
    float v0 = __int_as_float(p0.y), v1 = __int_as_float(p1.y);
    float v2 = __int_as_float(p2.y), v3 = __int_as_float(p3.y);
    acc.x = fmaf(v0, x0.x, acc.x); acc.y = fmaf(v0, x0.y, acc.y);
    acc.z = fmaf(v0, x0.z, acc.z); acc.w = fmaf(v0, x0.w, acc.w);
    acc.x = fmaf(v1, x1.x, acc.x); acc.y = fmaf(v1, x1.y, acc.y);
    acc.z = fmaf(v1, x1.z, acc.z); acc.w = fmaf(v1, x1.w, acc.w);
    acc.x = fmaf(v2, x2.x, acc.x); acc.y = fmaf(v2, x2.y, acc.y);
    acc.z = fmaf(v2, x2.z, acc.z); acc.w = fmaf(v2, x2.w, acc.w);
    acc.x = fmaf(v3, x3.x, acc.x); acc.y = fmaf(v3, x3.y, acc.y);
    acc.z = fmaf(v3, x3.z, acc.z); acc.w = fmaf(v3, x3.w, acc.w);
  }
  for (; j < e; ++j) {
    int2 p = edges[j];
    float4 x = X4[p.x * 64 + lane];
    float v = __int_as_float(p.y);
    acc.x = fmaf(v, x.x, acc.x); acc.y = fmaf(v, x.y, acc.y);
    acc.z = fmaf(v, x.z, acc.z); acc.w = fmaf(v, x.w, acc.w);
  }
  float4 sf = X4[row * 64 + lane];  // + I
  acc.x += sf.x; acc.y += sf.y; acc.z += sf.z; acc.w += sf.w;
  ((float4*)Y)[row * 64 + lane] = acc;
}

// ============================ BatchNorm stats ============================

__global__ __launch_bounds__(256) void colstats_kernel(const float* __restrict__ X,
                                                       float* __restrict__ sum,
                                                       float* __restrict__ sumsq) {
  const int c = threadIdx.x;  // one feature column per thread
  float s = 0.f, q = 0.f;
  for (int r = blockIdx.x; r < NNODES; r += gridDim.x) {
    float x = X[r * FEAT + c];
    s += x;
    q = fmaf(x, x, q);
  }
  atomicAdd(&sum[c], s);
  atomicAdd(&sumsq[c], q);
}

__global__ void bnfinal_kernel(const float* __restrict__ sum, const float* __restrict__ sumsq,
                               const float* __restrict__ gamma, const float* __restrict__ beta,
                               float* __restrict__ scale, float* __restrict__ shift) {
  int c = threadIdx.x;
  float mean = sum[c] * (1.f / NNODES);
  float var = sumsq[c] * (1.f / NNODES) - mean * mean;
  float inv = rsqrtf(var + EPS_BN);
  float sc = gamma[c] * inv;
  scale[c] = sc;
  shift[c] = beta[c] - mean * sc;
}

// ============================ launch ============================
// Workspace budget note: only ONE N*F temporary lives in d_ws; the out1
// intermediate uses d_out itself (legal: spmm2 reads only bufT, writes d_out;
// every stage fully overwrites its destination so 0xAA re-poison is harmless).
// Total d_ws need: 102.4MB (bufT) + 1.2MB (CSR ints) + 25.6MB (edges) + 4KB.

extern "C" void kernel_launch(void* const* d_in, const int* in_sizes, int n_in,
                              void* d_out, int out_size, void* d_ws, size_t ws_size,
                              hipStream_t stream) {
  const float* feature = (const float*)d_in[0];
  const int*   rows    = (const int*)d_in[1];
  const int*   cols    = (const int*)d_in[2];
  const float* vals    = (const float*)d_in[3];
  const float* W1      = (const float*)d_in[4];
  const float* W2      = (const float*)d_in[5];
  const float* gamma   = (const float*)d_in[6];
  const float* beta    = (const float*)d_in[7];
  float* out = (float*)d_out;

  // workspace layout (~129 MB)
  char* ws = (char*)d_ws;
  size_t nf = (size_t)NNODES * FEAT;
  float* bufT = (float*)ws;                 // support / t          (N*F)
  int* offsets = (int*)(bufT + nf);         // N+1
  int* cursor  = offsets + (NNODES + 1);    // N
  int* counts  = cursor + NNODES;           // N
  int2* edges  = (int2*)(((uintptr_t)(counts + NNODES) + 15) & ~(uintptr_t)15);  // E
  float* colsum   = (float*)(edges + NEDGES);
  float* colsumsq = colsum + FEAT;
  float* bnscale  = colsumsq + FEAT;
  float* bnshift  = bnscale + FEAT;

  hipMemsetAsync(counts, 0, NNODES * sizeof(int), stream);
  hipMemsetAsync(colsum, 0, 2 * FEAT * sizeof(float), stream);

  // CSR build (every call — inputs re-poisoned each launch)
  count_kernel<<<2048, 256, 0, stream>>>(rows, counts);
  scan_kernel<<<1, 1024, 0, stream>>>(counts, offsets, cursor);
  scatter_kernel<<<2048, 256, 0, stream>>>(rows, cols, vals, cursor, edges);

  dim3 ggrid((NNODES + 63) / 64, FEAT / 64);
  // support = feature @ W1           -> bufT
  gemm_kernel<false><<<ggrid, 256, 0, stream>>>(feature, W1, bufT, nullptr, nullptr);
  // out1 = (A+I) @ support           -> d_out (used as temporary)
  spmm_kernel<<<NNODES / 4, 256, 0, stream>>>(bufT, offsets, edges, out);
  // batch stats of out1
  colstats_kernel<<<1024, 256, 0, stream>>>(out, colsum, colsumsq);
  bnfinal_kernel<<<1, 256, 0, stream>>>(colsum, colsumsq, gamma, beta, bnscale, bnshift);
  // t = relu(BN(out1)) @ W2          -> bufT   (BN fused into A staging)
  gemm_kernel<true><<<ggrid, 256, 0, stream>>>(out, W2, bufT, bnscale, bnshift);
  // out = (A+I) @ t                  -> d_out  (reads bufT only; no alias)
  spmm_kernel<<<NNODES / 4, 256, 0, stream>>>(bufT, offsets, edges, out);
}

// Round 7
// 1412.989 us; speedup vs baseline: 1.4187x; 1.4187x over previous
//
#include <hip/hip_runtime.h>
#include <cstdint>

#define NNODES 100000
#define NEDGES 3200000
#define FEAT   256
#define EPS_BN 1e-5f
#define SCAN_BLK 1024
#define NSCAN ((NNODES + SCAN_BLK - 1) / SCAN_BLK)  // 98

// fp32 -> bf16 round-to-nearest-even
__device__ inline unsigned short f2bf(float f) {
  uint32_t u = __float_as_uint(f);
  uint32_t r = (u + 0x7fffu + ((u >> 16) & 1u)) >> 16;
  return (unsigned short)r;
}
__device__ inline float bf2f(unsigned short u) {
  return __uint_as_float(((uint32_t)u) << 16);
}

// ============================ CSR build ============================

__global__ void count_kernel(const int* __restrict__ rows, int* __restrict__ counts) {
  int stride = gridDim.x * blockDim.x;
  for (int e = blockIdx.x * blockDim.x + threadIdx.x; e < NEDGES; e += stride)
    atomicAdd(&counts[rows[e]], 1);
}

// hierarchical scan, phase 1: per-block exclusive scan + block totals
__global__ __launch_bounds__(1024) void scan1_kernel(const int* __restrict__ counts,
                                                     int* __restrict__ excl,
                                                     int* __restrict__ btot) {
  __shared__ int wsum[16];
  const int tid = threadIdx.x, lane = tid & 63, wid = tid >> 6;
  const int i = blockIdx.x * SCAN_BLK + tid;
  int x = (i < NNODES) ? counts[i] : 0;
  int v = x;
#pragma unroll
  for (int off = 1; off < 64; off <<= 1) {
    int u = __shfl_up(v, off);
    if (lane >= off) v += u;
  }
  if (lane == 63) wsum[wid] = v;
  __syncthreads();
  if (wid == 0 && lane < 16) {
    int wv = wsum[lane];
#pragma unroll
    for (int off = 1; off < 16; off <<= 1) {
      int u = __shfl_up(wv, off);
      if (lane >= off) wv += u;
    }
    wsum[lane] = wv;
  }
  __syncthreads();
  int base = (wid > 0) ? wsum[wid - 1] : 0;
  if (i < NNODES) excl[i] = base + v - x;
  if (tid == 0) btot[blockIdx.x] = wsum[15];
}

// phase 2: single block scans the 98 block totals (2 waves, 128 thr)
__global__ __launch_bounds__(128) void scan2_kernel(const int* __restrict__ btot,
                                                    int* __restrict__ bbase,
                                                    int* __restrict__ offs_end) {
  __shared__ int w0tot;
  const int tid = threadIdx.x, lane = tid & 63, wid = tid >> 6;
  int x = (tid < NSCAN) ? btot[tid] : 0;
  int v = x;
#pragma unroll
  for (int off = 1; off < 64; off <<= 1) {
    int u = __shfl_up(v, off);
    if (lane >= off) v += u;
  }
  if (wid == 0 && lane == 63) w0tot = v;
  __syncthreads();
  int incl = v + ((wid == 1) ? w0tot : 0);
  if (tid < NSCAN) bbase[tid] = incl - x;
  if (tid == NSCAN - 1) *offs_end = incl;  // offsets[NNODES] = E
}

// phase 3: add block bases
__global__ __launch_bounds__(1024) void scan3_kernel(const int* __restrict__ excl,
                                                     const int* __restrict__ bbase,
                                                     int* __restrict__ offsets,
                                                     int* __restrict__ cursor) {
  const int i = blockIdx.x * SCAN_BLK + threadIdx.x;
  if (i < NNODES) {
    int o = excl[i] + bbase[blockIdx.x];
    offsets[i] = o;
    cursor[i] = o;
  }
}

__global__ void scatter_kernel(const int* __restrict__ rows, const int* __restrict__ cols,
                               const float* __restrict__ vals, int* __restrict__ cursor,
                               int2* __restrict__ edges) {
  int stride = gridDim.x * blockDim.x;
  for (int e = blockIdx.x * blockDim.x + threadIdx.x; e < NEDGES; e += stride) {
    int r = rows[e];
    int pos = atomicAdd(&cursor[r], 1);
    edges[pos] = make_int2(cols[e], __float_as_int(vals[e]));
  }
}

// ============================ GEMM (fp32 vector, bf16 out) ============================
// C_bf16[M,256] = act(A_f32)[M,256] @ B_f32[256,256]. 128x128 tile, BK=16,
// 256 thr, 8x8/thread. Thread (tr,tc): rows tr*8..+7, cols {tc*4..+3, 64+tc*4..+3}.
// LDS reads per k: A 2x b128 (16-lane broadcast, 16 banks), B 2x b128 (2-way
// alias = free per m136). BN=true: A staged as relu(a*scale[k]+shift[k]).

template <bool BN>
__global__ __launch_bounds__(256) void gemm_kernel(const float* __restrict__ A,
                                                   const float* __restrict__ B,
                                                   unsigned short* __restrict__ C,
                                                   const float* __restrict__ scale,
                                                   const float* __restrict__ shift) {
  __shared__ float As[16][132];  // [k][m]
  __shared__ float Bs[16][132];  // [k][n]
  const int tid = threadIdx.x;
  const int row0 = blockIdx.x * 128;
  const int col0 = blockIdx.y * 128;
  const int tr = tid >> 4;  // 0..15
  const int tc = tid & 15;  // 0..15
  float acc[8][8] = {};

  for (int kt = 0; kt < 16; ++kt) {
    __syncthreads();
#pragma unroll
    for (int i = 0; i < 2; ++i) {
      int idx = tid + 256 * i;
      // A: 128 rows x 16 k = 512 float4, transpose into As[k][m]
      int ar = idx >> 2, ak = idx & 3;
      int grow = row0 + ar;
      float4 av = make_float4(0.f, 0.f, 0.f, 0.f);
      if (grow < NNODES) av = *(const float4*)&A[(size_t)grow * FEAT + kt * 16 + ak * 4];
      if (BN) {
        int kb = kt * 16 + ak * 4;
        float4 sc = *(const float4*)&scale[kb];
        float4 sh = *(const float4*)&shift[kb];
        av.x = fmaxf(0.f, fmaf(av.x, sc.x, sh.x));
        av.y = fmaxf(0.f, fmaf(av.y, sc.y, sh.y));
        av.z = fmaxf(0.f, fmaf(av.z, sc.z, sh.z));
        av.w = fmaxf(0.f, fmaf(av.w, sc.w, sh.w));
      }
      As[ak * 4 + 0][ar] = av.x;
      As[ak * 4 + 1][ar] = av.y;
      As[ak * 4 + 2][ar] = av.z;
      As[ak * 4 + 3][ar] = av.w;
      // B: 16 k x 128 n = 512 float4, natural layout
      int bk = idx >> 5, bq = idx & 31;
      float4 bv = *(const float4*)&B[(size_t)(kt * 16 + bk) * FEAT + col0 + bq * 4];
      *(float4*)&Bs[bk][bq * 4] = bv;
    }
    __syncthreads();
#pragma unroll
    for (int k = 0; k < 16; ++k) {
      float a0[8], b0[8];
      *(float4*)&a0[0] = *(const float4*)&As[k][tr * 8];
      *(float4*)&a0[4] = *(const float4*)&As[k][tr * 8 + 4];
      *(float4*)&b0[0] = *(const float4*)&Bs[k][tc * 4];
      *(float4*)&b0[4] = *(const float4*)&Bs[k][64 + tc * 4];
#pragma unroll
      for (int ii = 0; ii < 8; ++ii)
#pragma unroll
        for (int jj = 0; jj < 8; ++jj)
          acc[ii][jj] = fmaf(a0[ii], b0[jj], acc[ii][jj]);
    }
  }
#pragma unroll
  for (int i = 0; i < 8; ++i) {
    int r = row0 + tr * 8 + i;
    if (r < NNODES) {
      ushort4 u0, u1;
      u0.x = f2bf(acc[i][0]); u0.y = f2bf(acc[i][1]);
      u0.z = f2bf(acc[i][2]); u0.w = f2bf(acc[i][3]);
      u1.x = f2bf(acc[i][4]); u1.y = f2bf(acc[i][5]);
      u1.z = f2bf(acc[i][6]); u1.w = f2bf(acc[i][7]);
      *(ushort4*)&C[(size_t)r * FEAT + col0 + tc * 4] = u0;
      *(ushort4*)&C[(size_t)r * FEAT + col0 + 64 + tc * 4] = u1;
    }
  }
}

// ============================ SpMM: Y = (A+I) @ X ============================
// X is bf16 (51 MB -> L3-resident). One wave per dest row; lane holds 4 feats.
// fp32 accumulate, fp32 out.

__global__ __launch_bounds__(256) void spmm_kernel(const unsigned short* __restrict__ X,
                                                   const int* __restrict__ offsets,
                                                   const int2* __restrict__ edges,
                                                   float* __restrict__ Y) {
  const int lane = threadIdx.x & 63;
  const int row = blockIdx.x * 4 + (threadIdx.x >> 6);
  if (row >= NNODES) return;
  const int s = offsets[row], e = offsets[row + 1];
  const ushort4* __restrict__ X4 = (const ushort4*)X;  // node*64 + lane
  float4 acc = make_float4(0.f, 0.f, 0.f, 0.f);
  int j = s;
  for (; j + 4 <= e; j += 4) {
    int2 p0 = edges[j], p1 = edges[j + 1], p2 = edges[j + 2], p3 = edges[j + 3];
    ushort4 x0 = X4[p0.x * 64 + lane];
    ushort4 x1 = X4[p1.x * 64 + lane];
    ushort4 x2 = X4[p2.x * 64 + lane];
    ushort4 x3 = X4[p3.x * 64 + lane];
    float v0 = __int_as_float(p0.y), v1 = __int_as_float(p1.y);
    float v2 = __int_as_float(p2.y), v3 = __int_as_float(p3.y);
    acc.x = fmaf(v0, bf2f(x0.x), acc.x); acc.y = fmaf(v0, bf2f(x0.y), acc.y);
    acc.z = fmaf(v0, bf2f(x0.z), acc.z); acc.w = fmaf(v0, bf2f(x0.w), acc.w);
    acc.x = fmaf(v1, bf2f(x1.x), acc.x); acc.y = fmaf(v1, bf2f(x1.y), acc.y);
    acc.z = fmaf(v1, bf2f(x1.z), acc.z); acc.w = fmaf(v1, bf2f(x1.w), acc.w);
    acc.x = fmaf(v2, bf2f(x2.x), acc.x); acc.y = fmaf(v2, bf2f(x2.y), acc.y);
    acc.z = fmaf(v2, bf2f(x2.z), acc.z); acc.w = fmaf(v2, bf2f(x2.w), acc.w);
    acc.x = fmaf(v3, bf2f(x3.x), acc.x); acc.y = fmaf(v3, bf2f(x3.y), acc.y);
    acc.z = fmaf(v3, bf2f(x3.z), acc.z); acc.w = fmaf(v3, bf2f(x3.w), acc.w);
  }
  for (; j < e; ++j) {
    int2 p = edges[j];
    ushort4 x = X4[p.x * 64 + lane];
    float v = __int_as_float(p.y);
    acc.x = fmaf(v, bf2f(x.x), acc.x); acc.y = fmaf(v, bf2f(x.y), acc.y);
    acc.z = fmaf(v, bf2f(x.z), acc.z); acc.w = fmaf(v, bf2f(x.w), acc.w);
  }
  ushort4 sf = X4[row * 64 + lane];  // + I (self-loop)
  acc.x += bf2f(sf.x); acc.y += bf2f(sf.y);
  acc.z += bf2f(sf.z); acc.w += bf2f(sf.w);
  ((float4*)Y)[row * 64 + lane] = acc;
}

// ============================ BatchNorm stats ============================

__global__ __launch_bounds__(256) void colstats_kernel(const float* __restrict__ X,
                                                       float* __restrict__ sum,
                                                       float* __restrict__ sumsq) {
  const int c = threadIdx.x;
  float s = 0.f, q = 0.f;
  for (int r = blockIdx.x; r < NNODES; r += gridDim.x) {
    float x = X[(size_t)r * FEAT + c];
    s += x;
    q = fmaf(x, x, q);
  }
  atomicAdd(&sum[c], s);
  atomicAdd(&sumsq[c], q);
}

__global__ void bnfinal_kernel(const float* __restrict__ sum, const float* __restrict__ sumsq,
                               const float* __restrict__ gamma, const float* __restrict__ beta,
                               float* __restrict__ scale, float* __restrict__ shift) {
  int c = threadIdx.x;
  float mean = sum[c] * (1.f / NNODES);
  float var = sumsq[c] * (1.f / NNODES) - mean * mean;
  float inv = rsqrtf(var + EPS_BN);
  float sc = gamma[c] * inv;
  scale[c] = sc;
  shift[c] = beta[c] - mean * sc;
}

// ============================ launch ============================
// Dataflow (bufBf16 reused for support then t; out1 lives in d_out):
//   gemm1: feature@W1 -> bufBf16        spmm1: (A+I)bufBf16 -> d_out (fp32)
//   stats(d_out) -> scale/shift         gemm2: relu(BN(d_out))@W2 -> bufBf16
//   spmm2: (A+I)bufBf16 -> d_out        (spmm2 reads only bufBf16: no alias)
// ws need: 51.2MB (bf16 buf) + ~1.6MB (scan ints) + 25.6MB (edges) + 4KB.

extern "C" void kernel_launch(void* const* d_in, const int* in_sizes, int n_in,
                              void* d_out, int out_size, void* d_ws, size_t ws_size,
                              hipStream_t stream) {
  const float* feature = (const float*)d_in[0];
  const int*   rows    = (const int*)d_in[1];
  const int*   cols    = (const int*)d_in[2];
  const float* vals    = (const float*)d_in[3];
  const float* W1      = (const float*)d_in[4];
  const float* W2      = (const float*)d_in[5];
  const float* gamma   = (const float*)d_in[6];
  const float* beta    = (const float*)d_in[7];
  float* out = (float*)d_out;

  char* ws = (char*)d_ws;
  size_t nf = (size_t)NNODES * FEAT;
  unsigned short* bufBf16 = (unsigned short*)ws;        // N*F bf16
  int* excl    = (int*)(bufBf16 + nf);                  // N
  int* offsets = excl + NNODES;                         // N+1
  int* cursor  = offsets + (NNODES + 1);                // N
  int* counts  = cursor + NNODES;                       // N
  int* btot    = counts + NNODES;                       // 128
  int* bbase   = btot + 128;                            // 128
  int2* edges  = (int2*)(((uintptr_t)(bbase + 128) + 15) & ~(uintptr_t)15);  // E
  float* colsum   = (float*)(edges + NEDGES);
  float* colsumsq = colsum + FEAT;
  float* bnscale  = colsumsq + FEAT;
  float* bnshift  = bnscale + FEAT;

  hipMemsetAsync(counts, 0, NNODES * sizeof(int), stream);
  hipMemsetAsync(colsum, 0, 2 * FEAT * sizeof(float), stream);

  // CSR build
  count_kernel<<<2048, 256, 0, stream>>>(rows, counts);
  scan1_kernel<<<NSCAN, SCAN_BLK, 0, stream>>>(counts, excl, btot);
  scan2_kernel<<<1, 128, 0, stream>>>(btot, bbase, &offsets[NNODES]);
  scan3_kernel<<<NSCAN, SCAN_BLK, 0, stream>>>(excl, bbase, offsets, cursor);
  scatter_kernel<<<2048, 256, 0, stream>>>(rows, cols, vals, cursor, edges);

  dim3 ggrid((NNODES + 127) / 128, FEAT / 128);
  // support(bf16) = feature @ W1
  gemm_kernel<false><<<ggrid, 256, 0, stream>>>(feature, W1, bufBf16, nullptr, nullptr);
  // out1(fp32) = (A+I) @ support
  spmm_kernel<<<NNODES / 4, 256, 0, stream>>>(bufBf16, offsets, edges, out);
  // batch stats of out1
  colstats_kernel<<<1024, 256, 0, stream>>>(out, colsum, colsumsq);
  bnfinal_kernel<<<1, 256, 0, stream>>>(colsum, colsumsq, gamma, beta, bnscale, bnshift);
  // t(bf16) = relu(BN(out1)) @ W2  (BN fused into A staging)
  gemm_kernel<true><<<ggrid, 256, 0, stream>>>(out, W2, bufBf16, bnscale, bnshift);
  // out = (A+I) @ t
  spmm_kernel<<<NNODES / 4, 256, 0, stream>>>(bufBf16, offsets, edges, out);
}

// Round 8
// 1175.307 us; speedup vs baseline: 1.7056x; 1.2022x over previous
//
#include <hip/hip_runtime.h>
#include <cstdint>

#define NNODES 100000
#define NEDGES 3200000
#define FEAT   256
#define EPS_BN 1e-5f

// ---- bucketed CSR build params ----
#define BSHIFT 9                       // 512 rows per bucket
#define NBUCK  196                     // ceil(100000 / 512) = 196 (196*512 = 100352)
#define BCAP   20480                   // slack: mean 16327, sigma~127 -> ~32 sigma
#define PA_BLOCKS 2048
#define PA_CHUNK  1563                 // ceil(E / PA_BLOCKS); 2048*1563 >= E
#define PA_ITERS  7                    // ceil(1563/256)

// fp32 -> bf16 round-to-nearest-even
__device__ inline unsigned short f2bf(float f) {
  uint32_t u = __float_as_uint(f);
  uint32_t r = (u + 0x7fffu + ((u >> 16) & 1u)) >> 16;
  return (unsigned short)r;
}
__device__ inline float bf2f(unsigned short u) {
  return __uint_as_float(((uint32_t)u) << 16);
}

// ============================ CSR build (bucketed) ============================

__global__ void binit_kernel(int* __restrict__ bcur) {
  int i = threadIdx.x;
  if (i < NBUCK) bcur[i] = i * BCAP;
}

// Pass A: coarse scatter into 196 fixed-capacity bucket streams.
// Per block: LDS hist over buckets -> one global reservation per touched bucket
// -> line-dense writes (avg ~8 edges per bucket per block).
__global__ __launch_bounds__(256) void bucketA_kernel(const int* __restrict__ rows,
                                                      const int* __restrict__ cols,
                                                      const float* __restrict__ vals,
                                                      int* __restrict__ bcur,
                                                      int* __restrict__ srow,
                                                      int2* __restrict__ scolval) {
  __shared__ int hist[NBUCK];
  __shared__ int bres[NBUCK];
  __shared__ int cnt2[NBUCK];
  const int tid = threadIdx.x;
  const int c0 = blockIdx.x * PA_CHUNK;
  const int c1 = min(c0 + PA_CHUNK, NEDGES);
  for (int i = tid; i < NBUCK; i += 256) { hist[i] = 0; cnt2[i] = 0; }
  __syncthreads();
  int rr[PA_ITERS], cc[PA_ITERS], bb[PA_ITERS];
  float vv[PA_ITERS];
#pragma unroll
  for (int it = 0; it < PA_ITERS; ++it) {
    int e = c0 + it * 256 + tid;
    bool ok = e < c1;
    rr[it] = ok ? rows[e] : 0;
    cc[it] = ok ? cols[e] : 0;
    vv[it] = ok ? vals[e] : 0.f;
    bb[it] = ok ? (rr[it] >> BSHIFT) : -1;
    if (ok) atomicAdd(&hist[bb[it]], 1);
  }
  __syncthreads();
  if (tid < NBUCK) {
    int x = hist[tid];
    bres[tid] = (x > 0) ? atomicAdd(&bcur[tid], x) : 0;
  }
  __syncthreads();
#pragma unroll
  for (int it = 0; it < PA_ITERS; ++it) {
    if (bb[it] >= 0) {
      int l = atomicAdd(&cnt2[bb[it]], 1);
      int slot = bres[bb[it]] + l;
      srow[slot] = rr[it];
      scolval[slot] = make_int2(cc[it], __float_as_int(vv[it]));
    }
  }
}

// scan of the 196 bucket counts -> global bucket bases + total
__global__ __launch_bounds__(256) void bscan_kernel(const int* __restrict__ bcur,
                                                    int* __restrict__ gbase,
                                                    int* __restrict__ offs_end) {
  __shared__ int wsum[4];
  __shared__ int tot;
  const int tid = threadIdx.x, lane = tid & 63, wid = tid >> 6;
  int x = (tid < NBUCK) ? (bcur[tid] - tid * BCAP) : 0;
  int v = x;
#pragma unroll
  for (int off = 1; off < 64; off <<= 1) {
    int u = __shfl_up(v, off);
    if (lane >= off) v += u;
  }
  if (lane == 63) wsum[wid] = v;
  __syncthreads();
  if (tid == 0) {
    int s = 0;
#pragma unroll
    for (int w = 0; w < 4; ++w) { int t = wsum[w]; wsum[w] = s; s += t; }
    tot = s;
  }
  __syncthreads();
  if (tid < NBUCK) gbase[tid] = v - x + wsum[wid];
  if (tid == 0) *offs_end = tot;  // offsets[NNODES] = E
}

// Pass B: one block per bucket. LDS row-histogram -> in-LDS scan -> offsets
// write + fine scatter with LDS cursors into the bucket's contiguous slice.
__global__ __launch_bounds__(512) void bucketB_kernel(const int* __restrict__ srow,
                                                      const int2* __restrict__ scolval,
                                                      const int* __restrict__ bcur,
                                                      const int* __restrict__ gbase,
                                                      int* __restrict__ offsets,
                                                      int2* __restrict__ edges) {
  __shared__ int hist[512];
  __shared__ int wsum[8];
  const int b = blockIdx.x, tid = threadIdx.x;
  const int r0 = b << BSHIFT;
  const int sbase = b * BCAP;
  const int scount = bcur[b] - sbase;
  const int gb = gbase[b];
  hist[tid] = 0;
  __syncthreads();
  for (int j = tid; j < scount; j += 512)
    atomicAdd(&hist[srow[sbase + j] - r0], 1);
  __syncthreads();
  // exclusive scan of hist[512]
  const int lane = tid & 63, wid = tid >> 6;
  int x = hist[tid], v = x;
#pragma unroll
  for (int off = 1; off < 64; off <<= 1) {
    int u = __shfl_up(v, off);
    if (lane >= off) v += u;
  }
  if (lane == 63) wsum[wid] = v;
  __syncthreads();
  if (tid == 0) {
    int s = 0;
#pragma unroll
    for (int w = 0; w < 8; ++w) { int t = wsum[w]; wsum[w] = s; s += t; }
  }
  __syncthreads();
  int excl = gb + v - x + wsum[wid];
  int r = r0 + tid;
  if (r < NNODES) offsets[r] = excl;
  __syncthreads();
  hist[tid] = excl;  // becomes the global write cursor for this row
  __syncthreads();
  for (int j = tid; j < scount; j += 512) {
    int lr = srow[sbase + j] - r0;
    int2 cv = scolval[sbase + j];
    int pos = atomicAdd(&hist[lr], 1);
    edges[pos] = cv;
  }
}

// ============================ GEMM (fp32 vector, bf16 out) ============================
// identical to the round-7 passing kernel

template <bool BN>
__global__ __launch_bounds__(256) void gemm_kernel(const float* __restrict__ A,
                                                   const float* __restrict__ B,
                                                   unsigned short* __restrict__ C,
                                                   const float* __restrict__ scale,
                                                   const float* __restrict__ shift) {
  __shared__ float As[16][132];  // [k][m]
  __shared__ float Bs[16][132];  // [k][n]
  const int tid = threadIdx.x;
  const int row0 = blockIdx.x * 128;
  const int col0 = blockIdx.y * 128;
  const int tr = tid >> 4;
  const int tc = tid & 15;
  float acc[8][8] = {};

  for (int kt = 0; kt < 16; ++kt) {
    __syncthreads();
#pragma unroll
    for (int i = 0; i < 2; ++i) {
      int idx = tid + 256 * i;
      int ar = idx >> 2, ak = idx & 3;
      int grow = row0 + ar;
      float4 av = make_float4(0.f, 0.f, 0.f, 0.f);
      if (grow < NNODES) av = *(const float4*)&A[(size_t)grow * FEAT + kt * 16 + ak * 4];
      if (BN) {
        int kb = kt * 16 + ak * 4;
        float4 sc = *(const float4*)&scale[kb];
        float4 sh = *(const float4*)&shift[kb];
        av.x = fmaxf(0.f, fmaf(av.x, sc.x, sh.x));
        av.y = fmaxf(0.f, fmaf(av.y, sc.y, sh.y));
        av.z = fmaxf(0.f, fmaf(av.z, sc.z, sh.z));
        av.w = fmaxf(0.f, fmaf(av.w, sc.w, sh.w));
      }
      As[ak * 4 + 0][ar] = av.x;
      As[ak * 4 + 1][ar] = av.y;
      As[ak * 4 + 2][ar] = av.z;
      As[ak * 4 + 3][ar] = av.w;
      int bk = idx >> 5, bq = idx & 31;
      float4 bv = *(const float4*)&B[(size_t)(kt * 16 + bk) * FEAT + col0 + bq * 4];
      *(float4*)&Bs[bk][bq * 4] = bv;
    }
    __syncthreads();
#pragma unroll
    for (int k = 0; k < 16; ++k) {
      float a0[8], b0[8];
      *(float4*)&a0[0] = *(const float4*)&As[k][tr * 8];
      *(float4*)&a0[4] = *(const float4*)&As[k][tr * 8 + 4];
      *(float4*)&b0[0] = *(const float4*)&Bs[k][tc * 4];
      *(float4*)&b0[4] = *(const float4*)&Bs[k][64 + tc * 4];
#pragma unroll
      for (int ii = 0; ii < 8; ++ii)
#pragma unroll
        for (int jj = 0; jj < 8; ++jj)
          acc[ii][jj] = fmaf(a0[ii], b0[jj], acc[ii][jj]);
    }
  }
#pragma unroll
  for (int i = 0; i < 8; ++i) {
    int r = row0 + tr * 8 + i;
    if (r < NNODES) {
      ushort4 u0, u1;
      u0.x = f2bf(acc[i][0]); u0.y = f2bf(acc[i][1]);
      u0.z = f2bf(acc[i][2]); u0.w = f2bf(acc[i][3]);
      u1.x = f2bf(acc[i][4]); u1.y = f2bf(acc[i][5]);
      u1.z = f2bf(acc[i][6]); u1.w = f2bf(acc[i][7]);
      *(ushort4*)&C[(size_t)r * FEAT + col0 + tc * 4] = u0;
      *(ushort4*)&C[(size_t)r * FEAT + col0 + 64 + tc * 4] = u1;
    }
  }
}

// ============================ SpMM: Y = (A+I) @ X ============================
// identical to the round-7 passing kernel (bf16 gathers, fp32 accum/out)

__global__ __launch_bounds__(256) void spmm_kernel(const unsigned short* __restrict__ X,
                                                   const int* __restrict__ offsets,
                                                   const int2* __restrict__ edges,
                                                   float* __restrict__ Y) {
  const int lane = threadIdx.x & 63;
  const int row = blockIdx.x * 4 + (threadIdx.x >> 6);
  if (row >= NNODES) return;
  const int s = offsets[row], e = offsets[row + 1];
  const ushort4* __restrict__ X4 = (const ushort4*)X;
  float4 acc = make_float4(0.f, 0.f, 0.f, 0.f);
  int j = s;
  for (; j + 4 <= e; j += 4) {
    int2 p0 = edges[j], p1 = edges[j + 1], p2 = edges[j + 2], p3 = edges[j + 3];
    ushort4 x0 = X4[p0.x * 64 + lane];
    ushort4 x1 = X4[p1.x * 64 + lane];
    ushort4 x2 = X4[p2.x * 64 + lane];
    ushort4 x3 = X4[p3.x * 64 + lane];
    float v0 = __int_as_float(p0.y), v1 = __int_as_float(p1.y);
    float v2 = __int_as_float(p2.y), v3 = __int_as_float(p3.y);
    acc.x = fmaf(v0, bf2f(x0.x), acc.x); acc.y = fmaf(v0, bf2f(x0.y), acc.y);
    acc.z = fmaf(v0, bf2f(x0.z), acc.z); acc.w = fmaf(v0, bf2f(x0.w), acc.w);
    acc.x = fmaf(v1, bf2f(x1.x), acc.x); acc.y = fmaf(v1, bf2f(x1.y), acc.y);
    acc.z = fmaf(v1, bf2f(x1.z), acc.z); acc.w = fmaf(v1, bf2f(x1.w), acc.w);
    acc.x = fmaf(v2, bf2f(x2.x), acc.x); acc.y = fmaf(v2, bf2f(x2.y), acc.y);
    acc.z = fmaf(v2, bf2f(x2.z), acc.z); acc.w = fmaf(v2, bf2f(x2.w), acc.w);
    acc.x = fmaf(v3, bf2f(x3.x), acc.x); acc.y = fmaf(v3, bf2f(x3.y), acc.y);
    acc.z = fmaf(v3, bf2f(x3.z), acc.z); acc.w = fmaf(v3, bf2f(x3.w), acc.w);
  }
  for (; j < e; ++j) {
    int2 p = edges[j];
    ushort4 x = X4[p.x * 64 + lane];
    float v = __int_as_float(p.y);
    acc.x = fmaf(v, bf2f(x.x), acc.x); acc.y = fmaf(v, bf2f(x.y), acc.y);
    acc.z = fmaf(v, bf2f(x.z), acc.z); acc.w = fmaf(v, bf2f(x.w), acc.w);
  }
  ushort4 sf = X4[row * 64 + lane];
  acc.x += bf2f(sf.x); acc.y += bf2f(sf.y);
  acc.z += bf2f(sf.z); acc.w += bf2f(sf.w);
  ((float4*)Y)[row * 64 + lane] = acc;
}

// ============================ BatchNorm stats ============================

__global__ __launch_bounds__(256) void colstats_kernel(const float* __restrict__ X,
                                                       float* __restrict__ sum,
                                                       float* __restrict__ sumsq) {
  const int c = threadIdx.x;
  float s = 0.f, q = 0.f;
  for (int r = blockIdx.x; r < NNODES; r += gridDim.x) {
    float x = X[(size_t)r * FEAT + c];
    s += x;
    q = fmaf(x, x, q);
  }
  atomicAdd(&sum[c], s);
  atomicAdd(&sumsq[c], q);
}

__global__ void bnfinal_kernel(const float* __restrict__ sum, const float* __restrict__ sumsq,
                               const float* __restrict__ gamma, const float* __restrict__ beta,
                               float* __restrict__ scale, float* __restrict__ shift) {
  int c = threadIdx.x;
  float mean = sum[c] * (1.f / NNODES);
  float var = sumsq[c] * (1.f / NNODES) - mean * mean;
  float inv = rsqrtf(var + EPS_BN);
  float sc = gamma[c] * inv;
  scale[c] = sc;
  shift[c] = beta[c] - mean * sc;
}

// ============================ launch ============================
// ws layout (~77.5 MB total):
//   [shared 51.2MB region]: staged srow(16.1MB)+scolval(32.1MB) during CSR build,
//                           then bufBf16 (N*F bf16) -- gemm1 runs after passB.
//   [edges 25.6MB][offsets 0.4MB][bcur/gbase/colsum/... small]
// Dataflow: binit,passA,bscan,passB -> gemm1(bufBf16) -> spmm1(d_out) ->
//           stats -> gemm2(bufBf16) -> spmm2(d_out).

extern "C" void kernel_launch(void* const* d_in, const int* in_sizes, int n_in,
                              void* d_out, int out_size, void* d_ws, size_t ws_size,
                              hipStream_t stream) {
  const float* feature = (const float*)d_in[0];
  const int*   rows    = (const int*)d_in[1];
  const int*   cols    = (const int*)d_in[2];
  const float* vals    = (const float*)d_in[3];
  const float* W1      = (const float*)d_in[4];
  const float* W2      = (const float*)d_in[5];
  const float* gamma   = (const float*)d_in[6];
  const float* beta    = (const float*)d_in[7];
  float* out = (float*)d_out;

  char* ws = (char*)d_ws;
  size_t nf = (size_t)NNODES * FEAT;
  size_t stagedN = (size_t)NBUCK * BCAP;               // 4,014,080 slots
  // shared region: staged (srow+scolval) aliases bufBf16 (disjoint lifetimes)
  unsigned short* bufBf16 = (unsigned short*)ws;       // N*F bf16 = 51.2 MB
  int*  srow    = (int*)ws;                            // stagedN*4 = 16.1 MB
  int2* scolval = (int2*)(((uintptr_t)(srow + stagedN) + 15) & ~(uintptr_t)15);  // 32.1 MB
  char* after_shared = ws + ((nf * sizeof(unsigned short) + 255) & ~(size_t)255);
  int2* edges  = (int2*)after_shared;                  // E*8 = 25.6 MB
  int* offsets = (int*)(edges + NEDGES);               // N+1
  int* bcur    = offsets + (NNODES + 1);               // NBUCK
  int* gbase   = bcur + NBUCK;                         // NBUCK
  float* colsum   = (float*)(gbase + NBUCK);
  float* colsumsq = colsum + FEAT;
  float* bnscale  = colsumsq + FEAT;
  float* bnshift  = bnscale + FEAT;

  hipMemsetAsync(colsum, 0, 2 * FEAT * sizeof(float), stream);

  // bucketed CSR build (replaces count+scan+scatter)
  binit_kernel<<<1, 256, 0, stream>>>(bcur);
  bucketA_kernel<<<PA_BLOCKS, 256, 0, stream>>>(rows, cols, vals, bcur, srow, scolval);
  bscan_kernel<<<1, 256, 0, stream>>>(bcur, gbase, &offsets[NNODES]);
  bucketB_kernel<<<NBUCK, 512, 0, stream>>>(srow, scolval, bcur, gbase, offsets, edges);

  dim3 ggrid((NNODES + 127) / 128, FEAT / 128);
  // support(bf16) = feature @ W1   (bufBf16 now owns the shared region)
  gemm_kernel<false><<<ggrid, 256, 0, stream>>>(feature, W1, bufBf16, nullptr, nullptr);
  // out1(fp32) = (A+I) @ support
  spmm_kernel<<<NNODES / 4, 256, 0, stream>>>(bufBf16, offsets, edges, out);
  // batch stats of out1
  colstats_kernel<<<1024, 256, 0, stream>>>(out, colsum, colsumsq);
  bnfinal_kernel<<<1, 256, 0, stream>>>(colsum, colsumsq, gamma, beta, bnscale, bnshift);
  // t(bf16) = relu(BN(out1)) @ W2  (BN fused into A staging)
  gemm_kernel<true><<<ggrid, 256, 0, stream>>>(out, W2, bufBf16, bnscale, bnshift);
  // out = (A+I) @ t
  spmm_kernel<<<NNODES / 4, 256, 0, stream>>>(bufBf16, offsets, edges, out);
}

// Round 9
// 954.048 us; speedup vs baseline: 2.1012x; 1.2319x over previous
//
#include <hip/hip_runtime.h>
#include <cstdint>

#define NNODES 100000
#define NEDGES 3200000
#define FEAT   256
#define EPS_BN 1e-5f

// ---- bucketed CSR build params ----
#define BSHIFT 9
#define NBUCK  196
#define BCAP   20480
#define PA_BLOCKS 2048
#define PA_CHUNK  1563
#define PA_ITERS  7

typedef __attribute__((ext_vector_type(8))) short bf16x8;
typedef __attribute__((ext_vector_type(4))) float f32x4;

// fp32 -> bf16 round-to-nearest-even
__device__ inline unsigned short f2bf(float f) {
  uint32_t u = __float_as_uint(f);
  uint32_t r = (u + 0x7fffu + ((u >> 16) & 1u)) >> 16;
  return (unsigned short)r;
}
__device__ inline float bf2f(unsigned short u) {
  return __uint_as_float(((uint32_t)u) << 16);
}
__device__ inline uint32_t pack2(float a, float b) {
  return (uint32_t)f2bf(a) | ((uint32_t)f2bf(b) << 16);
}

// ============================ CSR build (bucketed) ============================

__global__ void binit_kernel(int* __restrict__ bcur) {
  int i = threadIdx.x;
  if (i < NBUCK) bcur[i] = i * BCAP;
}

__global__ __launch_bounds__(256) void bucketA_kernel(const int* __restrict__ rows,
                                                      const int* __restrict__ cols,
                                                      const float* __restrict__ vals,
                                                      int* __restrict__ bcur,
                                                      int* __restrict__ srow,
                                                      int2* __restrict__ scolval) {
  __shared__ int hist[NBUCK];
  __shared__ int bres[NBUCK];
  __shared__ int cnt2[NBUCK];
  const int tid = threadIdx.x;
  const int c0 = blockIdx.x * PA_CHUNK;
  const int c1 = min(c0 + PA_CHUNK, NEDGES);
  for (int i = tid; i < NBUCK; i += 256) { hist[i] = 0; cnt2[i] = 0; }
  __syncthreads();
  int rr[PA_ITERS], cc[PA_ITERS], bb[PA_ITERS];
  float vv[PA_ITERS];
#pragma unroll
  for (int it = 0; it < PA_ITERS; ++it) {
    int e = c0 + it * 256 + tid;
    bool ok = e < c1;
    rr[it] = ok ? rows[e] : 0;
    cc[it] = ok ? cols[e] : 0;
    vv[it] = ok ? vals[e] : 0.f;
    bb[it] = ok ? (rr[it] >> BSHIFT) : -1;
    if (ok) atomicAdd(&hist[bb[it]], 1);
  }
  __syncthreads();
  if (tid < NBUCK) {
    int x = hist[tid];
    bres[tid] = (x > 0) ? atomicAdd(&bcur[tid], x) : 0;
  }
  __syncthreads();
#pragma unroll
  for (int it = 0; it < PA_ITERS; ++it) {
    if (bb[it] >= 0) {
      int l = atomicAdd(&cnt2[bb[it]], 1);
      int slot = bres[bb[it]] + l;
      srow[slot] = rr[it];
      scolval[slot] = make_int2(cc[it], __float_as_int(vv[it]));
    }
  }
}

__global__ __launch_bounds__(256) void bscan_kernel(const int* __restrict__ bcur,
                                                    int* __restrict__ gbase,
                                                    int* __restrict__ offs_end) {
  __shared__ int wsum[4];
  __shared__ int tot;
  const int tid = threadIdx.x, lane = tid & 63, wid = tid >> 6;
  int x = (tid < NBUCK) ? (bcur[tid] - tid * BCAP) : 0;
  int v = x;
#pragma unroll
  for (int off = 1; off < 64; off <<= 1) {
    int u = __shfl_up(v, off);
    if (lane >= off) v += u;
  }
  if (lane == 63) wsum[wid] = v;
  __syncthreads();
  if (tid == 0) {
    int s = 0;
#pragma unroll
    for (int w = 0; w < 4; ++w) { int t = wsum[w]; wsum[w] = s; s += t; }
    tot = s;
  }
  __syncthreads();
  if (tid < NBUCK) gbase[tid] = v - x + wsum[wid];
  if (tid == 0) *offs_end = tot;
}

__global__ __launch_bounds__(512) void bucketB_kernel(const int* __restrict__ srow,
                                                      const int2* __restrict__ scolval,
                                                      const int* __restrict__ bcur,
                                                      const int* __restrict__ gbase,
                                                      int* __restrict__ offsets,
                                                      int2* __restrict__ edges) {
  __shared__ int hist[512];
  __shared__ int wsum[8];
  const int b = blockIdx.x, tid = threadIdx.x;
  const int r0 = b << BSHIFT;
  const int sbase = b * BCAP;
  const int scount = bcur[b] - sbase;
  const int gb = gbase[b];
  hist[tid] = 0;
  __syncthreads();
  for (int j = tid; j < scount; j += 512)
    atomicAdd(&hist[srow[sbase + j] - r0], 1);
  __syncthreads();
  const int lane = tid & 63, wid = tid >> 6;
  int x = hist[tid], v = x;
#pragma unroll
  for (int off = 1; off < 64; off <<= 1) {
    int u = __shfl_up(v, off);
    if (lane >= off) v += u;
  }
  if (lane == 63) wsum[wid] = v;
  __syncthreads();
  if (tid == 0) {
    int s = 0;
#pragma unroll
    for (int w = 0; w < 8; ++w) { int t = wsum[w]; wsum[w] = s; s += t; }
  }
  __syncthreads();
  int excl = gb + v - x + wsum[wid];
  int r = r0 + tid;
  if (r < NNODES) offsets[r] = excl;
  __syncthreads();
  hist[tid] = excl;
  __syncthreads();
  for (int j = tid; j < scount; j += 512) {
    int lr = srow[sbase + j] - r0;
    int2 cv = scolval[sbase + j];
    int pos = atomicAdd(&hist[lr], 1);
    edges[pos] = cv;
  }
}

// ============================ W transpose prep ============================
// Wt[n][k] = bf16(W[k][n]); one block per matrix.

__global__ __launch_bounds__(256) void wtprep_kernel(const float* __restrict__ W1,
                                                     const float* __restrict__ W2,
                                                     unsigned short* __restrict__ Wt1,
                                                     unsigned short* __restrict__ Wt2) {
  const float* W = (blockIdx.x == 0) ? W1 : W2;
  unsigned short* Wt = (blockIdx.x == 0) ? Wt1 : Wt2;
  const int n = threadIdx.x;
  for (int k = 0; k < FEAT; ++k)
    Wt[n * FEAT + k] = f2bf(W[k * FEAT + n]);
}

// ============================ GEMM (MFMA bf16, bf16 out) ============================
// C_bf16[M,256] = act(A_f32)[M,256] @ W[256,256], W pre-transposed bf16 Wt[n][k].
// Block: 128 M x 256 N (full width), 512 thr = 8 waves (4M x 2N), wave tile 32x128.
// mfma_f32_16x16x32_bf16; frag k-mapping identical for A and B (k-permutation
// cancels in the dot product). C/D layout (verified): col=lane&15, row=(lane>>4)*4+r.
// LDS stride 40 ushorts -> b128 frag reads are 2-way bank aliases (free).
// BN=true: A staged as relu(a*scale[k]+shift[k]) before bf16 conversion.

template <bool BN>
__global__ __launch_bounds__(512) void gemm_mfma_kernel(const float* __restrict__ A,
                                                        const unsigned short* __restrict__ Wt,
                                                        unsigned short* __restrict__ C,
                                                        const float* __restrict__ scale,
                                                        const float* __restrict__ shift) {
  __shared__ unsigned short As[128][40];
  __shared__ unsigned short Bs[256][40];
  const int tid = threadIdx.x;
  const int lane = tid & 63;
  const int wid = tid >> 6;      // 0..7
  const int wm = wid >> 1;       // 0..3  -> m offset wm*32
  const int wn = wid & 1;        // 0..1  -> n offset wn*128
  const int row0 = blockIdx.x * 128;

  f32x4 acc[2][8];
#pragma unroll
  for (int fm = 0; fm < 2; ++fm)
#pragma unroll
    for (int fn = 0; fn < 8; ++fn)
      acc[fm][fn] = (f32x4){0.f, 0.f, 0.f, 0.f};

  const int arow = lane & 15;
  const int akb = (lane >> 4) * 8;

  for (int k0 = 0; k0 < FEAT; k0 += 32) {
    __syncthreads();
    // stage A: 128 rows x 32 k (fp32 -> bf16, optional BN+ReLU)
    {
      int row = tid >> 2, ks = (tid & 3) * 8;
      int gr = row0 + row;
      float4 f0 = make_float4(0.f, 0.f, 0.f, 0.f);
      float4 f1 = make_float4(0.f, 0.f, 0.f, 0.f);
      if (gr < NNODES) {
        f0 = *(const float4*)&A[(size_t)gr * FEAT + k0 + ks];
        f1 = *(const float4*)&A[(size_t)gr * FEAT + k0 + ks + 4];
      }
      if (BN) {
        float4 sc0 = *(const float4*)&scale[k0 + ks];
        float4 sh0 = *(const float4*)&shift[k0 + ks];
        float4 sc1 = *(const float4*)&scale[k0 + ks + 4];
        float4 sh1 = *(const float4*)&shift[k0 + ks + 4];
        f0.x = fmaxf(0.f, fmaf(f0.x, sc0.x, sh0.x));
        f0.y = fmaxf(0.f, fmaf(f0.y, sc0.y, sh0.y));
        f0.z = fmaxf(0.f, fmaf(f0.z, sc0.z, sh0.z));
        f0.w = fmaxf(0.f, fmaf(f0.w, sc0.w, sh0.w));
        f1.x = fmaxf(0.f, fmaf(f1.x, sc1.x, sh1.x));
        f1.y = fmaxf(0.f, fmaf(f1.y, sc1.y, sh1.y));
        f1.z = fmaxf(0.f, fmaf(f1.z, sc1.z, sh1.z));
        f1.w = fmaxf(0.f, fmaf(f1.w, sc1.w, sh1.w));
      }
      uint4 pk;
      pk.x = pack2(f0.x, f0.y);
      pk.y = pack2(f0.z, f0.w);
      pk.z = pack2(f1.x, f1.y);
      pk.w = pack2(f1.z, f1.w);
      *(uint4*)&As[row][ks] = pk;
    }
    // stage B: 256 n x 32 k from Wt (already bf16, k-contiguous)
    {
      int n = tid >> 1, ks = (tid & 1) * 16;
      uint4 w0 = *(const uint4*)&Wt[n * FEAT + k0 + ks];
      uint4 w1 = *(const uint4*)&Wt[n * FEAT + k0 + ks + 8];
      *(uint4*)&Bs[n][ks] = w0;
      *(uint4*)&Bs[n][ks + 8] = w1;
    }
    __syncthreads();

    bf16x8 af[2], bfr[8];
#pragma unroll
    for (int fm = 0; fm < 2; ++fm)
      af[fm] = *(const bf16x8*)&As[wm * 32 + fm * 16 + arow][akb];
#pragma unroll
    for (int fn = 0; fn < 8; ++fn)
      bfr[fn] = *(const bf16x8*)&Bs[wn * 128 + fn * 16 + arow][akb];
#pragma unroll
    for (int fm = 0; fm < 2; ++fm)
#pragma unroll
      for (int fn = 0; fn < 8; ++fn)
        acc[fm][fn] = __builtin_amdgcn_mfma_f32_16x16x32_bf16(af[fm], bfr[fn], acc[fm][fn], 0, 0, 0);
  }

  // epilogue: C/D layout col=lane&15, row=(lane>>4)*4+r
  const int col = lane & 15;
  const int r4 = (lane >> 4) * 4;
#pragma unroll
  for (int fm = 0; fm < 2; ++fm) {
#pragma unroll
    for (int r = 0; r < 4; ++r) {
      int gr = row0 + wm * 32 + fm * 16 + r4 + r;
      if (gr < NNODES) {
#pragma unroll
        for (int fn = 0; fn < 8; ++fn)
          C[(size_t)gr * FEAT + wn * 128 + fn * 16 + col] = f2bf(acc[fm][fn][r]);
      }
    }
  }
}

// ============================ SpMM: Y = (A+I) @ X ============================
// bf16 gathers, fp32 accum/out. Unroll-8 with int4 edge loads (2 edges / 16 B)
// for deeper memory-level parallelism.

__device__ inline void fma_edge(float4& acc, ushort4 x, float v) {
  acc.x = fmaf(v, bf2f(x.x), acc.x);
  acc.y = fmaf(v, bf2f(x.y), acc.y);
  acc.z = fmaf(v, bf2f(x.z), acc.z);
  acc.w = fmaf(v, bf2f(x.w), acc.w);
}

__global__ __launch_bounds__(256) void spmm_kernel(const unsigned short* __restrict__ X,
                                                   const int* __restrict__ offsets,
                                                   const int2* __restrict__ edges,
                                                   float* __restrict__ Y) {
  const int lane = threadIdx.x & 63;
  const int row = blockIdx.x * 4 + (threadIdx.x >> 6);
  if (row >= NNODES) return;
  const int s = offsets[row], e = offsets[row + 1];
  const ushort4* __restrict__ X4 = (const ushort4*)X;
  const int4* __restrict__ E2 = (const int4*)edges;  // 2 edges per int4
  float4 acc = make_float4(0.f, 0.f, 0.f, 0.f);
  int j = s;
  if ((j & 1) && j < e) {  // align to even edge index for int4 loads
    int2 p = edges[j];
    fma_edge(acc, X4[p.x * 64 + lane], __int_as_float(p.y));
    ++j;
  }
  for (; j + 8 <= e; j += 8) {
    int4 q0 = E2[(j >> 1) + 0];
    int4 q1 = E2[(j >> 1) + 1];
    int4 q2 = E2[(j >> 1) + 2];
    int4 q3 = E2[(j >> 1) + 3];
    ushort4 x0 = X4[q0.x * 64 + lane];
    ushort4 x1 = X4[q0.z * 64 + lane];
    ushort4 x2 = X4[q1.x * 64 + lane];
    ushort4 x3 = X4[q1.z * 64 + lane];
    ushort4 x4 = X4[q2.x * 64 + lane];
    ushort4 x5 = X4[q2.z * 64 + lane];
    ushort4 x6 = X4[q3.x * 64 + lane];
    ushort4 x7 = X4[q3.z * 64 + lane];
    fma_edge(acc, x0, __int_as_float(q0.y));
    fma_edge(acc, x1, __int_as_float(q0.w));
    fma_edge(acc, x2, __int_as_float(q1.y));
    fma_edge(acc, x3, __int_as_float(q1.w));
    fma_edge(acc, x4, __int_as_float(q2.y));
    fma_edge(acc, x5, __int_as_float(q2.w));
    fma_edge(acc, x6, __int_as_float(q3.y));
    fma_edge(acc, x7, __int_as_float(q3.w));
  }
  for (; j + 2 <= e; j += 2) {
    int4 q = E2[j >> 1];
    ushort4 xa = X4[q.x * 64 + lane];
    ushort4 xb = X4[q.z * 64 + lane];
    fma_edge(acc, xa, __int_as_float(q.y));
    fma_edge(acc, xb, __int_as_float(q.w));
  }
  if (j < e) {
    int2 p = edges[j];
    fma_edge(acc, X4[p.x * 64 + lane], __int_as_float(p.y));
  }
  ushort4 sf = X4[row * 64 + lane];  // + I
  acc.x += bf2f(sf.x); acc.y += bf2f(sf.y);
  acc.z += bf2f(sf.z); acc.w += bf2f(sf.w);
  ((float4*)Y)[row * 64 + lane] = acc;
}

// ============================ BatchNorm stats ============================

__global__ __launch_bounds__(256) void colstats_kernel(const float* __restrict__ X,
                                                       float* __restrict__ sum,
                                                       float* __restrict__ sumsq) {
  const int c = threadIdx.x;
  float s = 0.f, q = 0.f;
  for (int r = blockIdx.x; r < NNODES; r += gridDim.x) {
    float x = X[(size_t)r * FEAT + c];
    s += x;
    q = fmaf(x, x, q);
  }
  atomicAdd(&sum[c], s);
  atomicAdd(&sumsq[c], q);
}

__global__ void bnfinal_kernel(const float* __restrict__ sum, const float* __restrict__ sumsq,
                               const float* __restrict__ gamma, const float* __restrict__ beta,
                               float* __restrict__ scale, float* __restrict__ shift) {
  int c = threadIdx.x;
  float mean = sum[c] * (1.f / NNODES);
  float var = sumsq[c] * (1.f / NNODES) - mean * mean;
  float inv = rsqrtf(var + EPS_BN);
  float sc = gamma[c] * inv;
  scale[c] = sc;
  shift[c] = beta[c] - mean * sc;
}

// ============================ launch ============================
// ws (~78 MB): [shared 51.2MB: srow+scolval during CSR build, then bufBf16]
// [edges 25.6MB][offsets][bcur][gbase][colsum|sumsq|scale|shift][Wt1][Wt2]

extern "C" void kernel_launch(void* const* d_in, const int* in_sizes, int n_in,
                              void* d_out, int out_size, void* d_ws, size_t ws_size,
                              hipStream_t stream) {
  const float* feature = (const float*)d_in[0];
  const int*   rows    = (const int*)d_in[1];
  const int*   cols    = (const int*)d_in[2];
  const float* vals    = (const float*)d_in[3];
  const float* W1      = (const float*)d_in[4];
  const float* W2      = (const float*)d_in[5];
  const float* gamma   = (const float*)d_in[6];
  const float* beta    = (const float*)d_in[7];
  float* out = (float*)d_out;

  char* ws = (char*)d_ws;
  size_t nf = (size_t)NNODES * FEAT;
  size_t stagedN = (size_t)NBUCK * BCAP;
  unsigned short* bufBf16 = (unsigned short*)ws;  // 51.2 MB, aliases staged
  int*  srow    = (int*)ws;
  int2* scolval = (int2*)(((uintptr_t)(srow + stagedN) + 15) & ~(uintptr_t)15);
  char* after_shared = ws + ((nf * sizeof(unsigned short) + 255) & ~(size_t)255);
  int2* edges  = (int2*)after_shared;             // 25.6 MB, 16B-aligned
  int* offsets = (int*)(edges + NEDGES);
  int* bcur    = offsets + (NNODES + 1);
  int* gbase   = bcur + NBUCK;
  float* colsum   = (float*)(gbase + NBUCK);
  float* colsumsq = colsum + FEAT;
  float* bnscale  = colsumsq + FEAT;
  float* bnshift  = bnscale + FEAT;
  unsigned short* Wt1 = (unsigned short*)(bnshift + FEAT);
  unsigned short* Wt2 = Wt1 + FEAT * FEAT;

  hipMemsetAsync(colsum, 0, 2 * FEAT * sizeof(float), stream);

  // bucketed CSR build
  binit_kernel<<<1, 256, 0, stream>>>(bcur);
  bucketA_kernel<<<PA_BLOCKS, 256, 0, stream>>>(rows, cols, vals, bcur, srow, scolval);
  bscan_kernel<<<1, 256, 0, stream>>>(bcur, gbase, &offsets[NNODES]);
  bucketB_kernel<<<NBUCK, 512, 0, stream>>>(srow, scolval, bcur, gbase, offsets, edges);

  // W transposes (independent of CSR)
  wtprep_kernel<<<2, 256, 0, stream>>>(W1, W2, Wt1, Wt2);

  const int gblocks = (NNODES + 127) / 128;  // 782
  // support(bf16) = feature @ W1
  gemm_mfma_kernel<false><<<gblocks, 512, 0, stream>>>(feature, Wt1, bufBf16, nullptr, nullptr);
  // out1(fp32) = (A+I) @ support
  spmm_kernel<<<NNODES / 4, 256, 0, stream>>>(bufBf16, offsets, edges, out);
  // batch stats
  colstats_kernel<<<1024, 256, 0, stream>>>(out, colsum, colsumsq);
  bnfinal_kernel<<<1, 256, 0, stream>>>(colsum, colsumsq, gamma, beta, bnscale, bnshift);
  // t(bf16) = relu(BN(out1)) @ W2
  gemm_mfma_kernel<true><<<gblocks, 512, 0, stream>>>(out, Wt2, bufBf16, bnscale, bnshift);
  // out = (A+I) @ t
  spmm_kernel<<<NNODES / 4, 256, 0, stream>>>(bufBf16, offsets, edges, out);
}